// Round 7
// baseline (420.929 us; speedup 1.0000x reference)
//
#include <hip/hip_runtime.h>
#include <hip/hip_bf16.h>

// EnhancedGNNEncoder round 7 (= round 6 with the bf162 constructor fixed):
//  - Gram-MFMA distances: d_ij = sqrt(|xc_j|^2+|xr_i|^2-2*xc_j.xr_i); cross
//    term is one MFMA whose operands are the registers each lane already holds.
//  - agg / x_acc accumulated via packed-bf16 atomics (global_atomic_pk_add_bf16).
//  - attention gate folded into stage-2 epilogue (partial dots in registers).
//  - k_wswz fused into k_pack.
// MFMA 16x16x32: A[m=lane&15][k=quad*8+j], B[k=quad*8+j][n=lane&15],
//                D col=lane&15, row=quad*4+reg.

#define TE 16
#define TN 16
#define PAD 40

typedef __attribute__((ext_vector_type(8))) short bf16x8;
typedef __attribute__((ext_vector_type(4))) float f32x4;

__device__ __forceinline__ float siluf(float v) { return v / (1.f + __expf(-v)); }
__device__ __forceinline__ float sigmf(float v) { return 1.f / (1.f + __expf(-v)); }
__device__ __forceinline__ short f2bs(float f) {
  union { __hip_bfloat16 b; short s; } u;
  u.b = __float2bfloat16(f);
  return u.s;
}
__device__ __forceinline__ __hip_bfloat162 mk_bf162(float v0, float v1) {
  __hip_bfloat162 r;
  r.x = __float2bfloat16(v0);
  r.y = __float2bfloat16(v1);
  return r;
}

// ---- pack: weight swizzle + attrS + h_bf16 + per-node prep ----
__global__ __launch_bounds__(256) void k_pack(
    const float* __restrict__ h, const float* __restrict__ x,
    const float* __restrict__ attr, const float* __restrict__ cw,
    const float* __restrict__ rad_w, const float* __restrict__ e_w1,
    const float* __restrict__ e_w2, const float* __restrict__ c_w1,
    const float* __restrict__ n_w1, const float* __restrict__ n_w2,
    const float* __restrict__ c_w2,
    __hip_bfloat16* __restrict__ wz_rad, __hip_bfloat16* __restrict__ wz_e1,
    __hip_bfloat16* __restrict__ wz_e2, __hip_bfloat16* __restrict__ wz_c1,
    __hip_bfloat16* __restrict__ wz_n1, __hip_bfloat16* __restrict__ wz_n2,
    __hip_bfloat16* __restrict__ wz_c2,
    __hip_bfloat16* __restrict__ attrS, __hip_bfloat16* __restrict__ hb,
    float* __restrict__ pooled_x, int* __restrict__ chsum, int Nn) {
  int idx = blockIdx.x * 256 + threadIdx.x;
  if (idx < 165888) {  // weight swizzle
    int i = idx;
    if (i >= 163840) {  // c_w2: [128][14] -> [4][16][32], n=14,15 zero
      int base = i - 163840;
      int k = base >> 4, n = base & 15;
      wz_c2[(size_t)(k >> 5) * 512 + n * 32 + (k & 31)] =
          (n < 14) ? __float2bfloat16(c_w2[k * 14 + n]) : __float2bfloat16(0.f);
      return;
    }
    const float* W;
    __hip_bfloat16* O;
    int base;
    if (i < 32768) { W = rad_w; O = wz_rad; base = i; }
    else if (i < 81920) { W = e_w1; O = wz_e1; base = i - 32768; }
    else if (i < 98304) { W = e_w2; O = wz_e2; base = i - 81920; }
    else if (i < 114688) { W = c_w1; O = wz_c1; base = i - 98304; }
    else if (i < 147456) { W = n_w1; O = wz_n1; base = i - 114688; }
    else { W = n_w2; O = wz_n2; base = i - 147456; }
    int k = base >> 7, n = base & 127;
    O[(size_t)((k >> 5) * 128 + n) * 32 + (k & 31)] = __float2bfloat16(W[base]);
    return;
  }
  idx -= 165888;
  int na = Nn * 256, nh = Nn * 128;
  if (idx < na) {
    int n = idx >> 8, r = idx & 255, i2 = r >> 4, a = r & 15;
    float v = 0.f;
    if (i2 < 14) v = attr[(size_t)n * 224 + i2 * 16 + a] * cw[(size_t)n * 14 + i2];
    attrS[(size_t)n * 256 + a * 16 + i2] = __float2bfloat16(v);
    return;
  }
  idx -= na;
  if (idx < nh) {
    hb[idx] = __float2bfloat16(h[idx]);
    return;
  }
  idx -= nh;
  if (idx >= Nn) return;
  int n = idx;
  int cnt = 0;
  float sx = 0.f, sy = 0.f, sz = 0.f;
#pragma unroll
  for (int c = 0; c < 14; c++) {
    float w = cw[n * 14 + c];
    if (w != 0.f) {
      cnt++;
      sx += x[n * 42 + c * 3 + 0];
      sy += x[n * 42 + c * 3 + 1];
      sz += x[n * 42 + c * 3 + 2];
    }
  }
  chsum[n] = cnt;
  float inv = 1.f / (float)(cnt > 0 ? cnt : 1);
  pooled_x[n * 3 + 0] = sx * inv;
  pooled_x[n * 3 + 1] = sy * inv;
  pooled_x[n * 3 + 2] = sz * inv;
}

// ---- merged: radial einsum + rad GEMM + edge MLP + gate + roller + scatters ----
__global__ __launch_bounds__(256, 4) void k_edge(
    const __hip_bfloat16* __restrict__ hb, const float* __restrict__ x,
    const __hip_bfloat16* __restrict__ attrS,
    const int* __restrict__ row, const int* __restrict__ col,
    const float* __restrict__ pooled_x, const int* __restrict__ chsum,
    const __hip_bfloat16* __restrict__ wz_rad, const float* __restrict__ rad_b,
    const __hip_bfloat16* __restrict__ wz_e1, const float* __restrict__ e_b1,
    const __hip_bfloat16* __restrict__ wz_e2, const float* __restrict__ e_b2,
    const float* __restrict__ att_w, const float* __restrict__ att_b,
    const __hip_bfloat16* __restrict__ wz_c1, const float* __restrict__ c_b1,
    const __hip_bfloat16* __restrict__ wz_c2, const float* __restrict__ c_b2,
    unsigned* __restrict__ cnt_row, unsigned* __restrict__ cnt_col,
    __hip_bfloat162* __restrict__ x_acc, __hip_bfloat162* __restrict__ agg, int Ee) {
  __shared__ __hip_bfloat16 sA[12][16][PAD];  // [h_row | h_col | radf] K=384
  __shared__ __hip_bfloat16 sW[8][16][PAD];   // sRad / sT(0..3),sU(4..7),sV(0..3)
  __shared__ float s_xr[TE][42];
  __shared__ float s_pc[TE][3];
  __shared__ float s_cm[TE][14];
  __shared__ float s_pool[TE][14];
  __shared__ float s_red[TE][64];
  __shared__ float s_att[TE], s_rn[TE];
  __shared__ int s_row[TE], s_col[TE], s_cs[TE];

  const int t = threadIdx.x;
  const int e0 = blockIdx.x * TE;
  const int ne = min(TE, Ee - e0);

  if (t < TE) {
    int e = e0 + min(t, ne - 1);
    s_row[t] = row[e];
    s_col[t] = col[e];
    s_cs[t] = chsum[s_row[t]];
    if (t < ne) {
      atomicAdd(&cnt_row[s_row[t]], 1u);
      atomicAdd(&cnt_col[s_col[t]], 1u);
    }
  }
  __syncthreads();

  // h staging -> sA[0..7]: pure bf16 int4 copy
  for (int i = t; i < TE * 32; i += 256) {
    int half = i >> 8;
    int m = (i >> 4) & 15, c8 = i & 15;
    int kb = (c8 >> 2) + half * 4, kk = (c8 & 3) * 8;
    int node = half ? s_col[m] : s_row[m];
    *(int4*)&sA[kb][m][kk] = *(const int4*)&hb[(size_t)node * 128 + c8 * 8];
  }
  if (t < TE * 3) {
    int e = t / 3, d = t % 3;
    s_pc[e][d] = pooled_x[(size_t)s_col[e] * 3 + d];
  }

  const int lane = t & 63, wave = t >> 6, quad = lane >> 4, mr = lane & 15;
  const int n0 = wave * 32;
  const float aw0 = att_w[n0 + mr], aw1 = att_w[n0 + 16 + mr];
  const float att_b0 = att_b[0];

  // ---- einsum: each wave owns 4 edges ----
  f32x4 zacc = {0.f, 0.f, 0.f, 0.f};
  const bf16x8 zero8 = {0, 0, 0, 0, 0, 0, 0, 0};
#pragma unroll
  for (int p = 0; p < 4; p++) {
    const int e = wave * 4 + p;
    const int re = s_row[e], ce = s_col[e];
    const int mrc = min(mr, 13);   // clamp: rows 14,15 compute garbage dists,
                                   // killed downstream by attrS zero-padding
    const float* xp = x + (size_t)re * 42 + mrc * 3;
    const float xr0 = xp[0], xr1 = xp[1], xr2 = xp[2];
    const float* xq = x + (size_t)ce * 42 + mrc * 3;
    const float xc0 = xq[0], xc1 = xq[1], xc2 = xq[2];
    if (quad == 0 && mr < 14) {
      s_xr[e][mr * 3 + 0] = xr0;
      s_xr[e][mr * 3 + 1] = xr1;
      s_xr[e][mr * 3 + 2] = xr2;
    }
    bf16x8 bC = zero8, aR = zero8;
    if (quad < 2) {
      bC = *(const bf16x8*)&attrS[(size_t)ce * 256 + mr * 16 + quad * 8];
      aR = *(const bf16x8*)&attrS[(size_t)re * 256 + mr * 16 + quad * 8];
    }
    // Gram cross-term: G[row=j][col=i] = xc_j . xr_i  (K=3, operands in-regs)
    bf16x8 aX = zero8, bX = zero8;
    if (quad == 0) {
      aX[0] = f2bs(xc0); aX[1] = f2bs(xc1); aX[2] = f2bs(xc2);
      bX[0] = f2bs(xr0); bX[1] = f2bs(xr1); bX[2] = f2bs(xr2);
    }
    f32x4 G = __builtin_amdgcn_mfma_f32_16x16x32_bf16(aX, bX, zacc, 0, 0, 0);
    const float nr = xr0 * xr0 + xr1 * xr1 + xr2 * xr2;
    const float nc = xc0 * xc0 + xc1 * xc1 + xc2 * xc2;
    float dD[4];
#pragma unroll
    for (int r = 0; r < 4; r++) {
      float ncj = __shfl(nc, quad * 4 + r);
      dD[r] = sqrtf(fmaxf(ncj + nr - 2.f * G[r], 0.f));
    }
    // transpose dists (D-layout) -> A-frag aD[m=i][k=j]
    bf16x8 aD;
#pragma unroll
    for (int jj = 0; jj < 8; jj++) {
      const int qs = (quad * 2 + (jj >> 2)) & 3;
      float dv = __shfl(dD[jj & 3], (qs << 4) | mr);
      if (quad >= 2) dv = 0.f;
      aD[jj] = f2bs(dv);
    }
    f32x4 m1 = __builtin_amdgcn_mfma_f32_16x16x32_bf16(aD, bC, zacc, 0, 0, 0);
    bf16x8 bM;
#pragma unroll
    for (int jj = 0; jj < 8; jj++) {
      const int qs = (quad * 2 + (jj >> 2)) & 3;
      float mv = __shfl(m1[jj & 3], (qs << 4) | mr);
      if (quad >= 2) mv = 0.f;
      bM[jj] = f2bs(mv);
    }
    f32x4 rd = __builtin_amdgcn_mfma_f32_16x16x32_bf16(aR, bM, zacc, 0, 0, 0);
    float ss = rd[0] * rd[0] + rd[1] * rd[1] + rd[2] * rd[2] + rd[3] * rd[3];
    ss += __shfl_xor(ss, 32); ss += __shfl_xor(ss, 16); ss += __shfl_xor(ss, 8);
    ss += __shfl_xor(ss, 4);  ss += __shfl_xor(ss, 2);  ss += __shfl_xor(ss, 1);
    if (lane == 0) s_rn[e] = sqrtf(ss) + 1.0f;
#pragma unroll
    for (int r = 0; r < 4; r++) {
      const int aa = quad * 4 + r;
      sW[aa >> 1][e][((aa & 1) << 4) | mr] = __float2bfloat16(rd[r]);
    }
  }
  __syncthreads();

  // ---- rad GEMM: radf = (radial @ rad_w + rad_b)/rn -> sA[8..11] ----
  {
    f32x4 acc0 = zacc, acc1 = zacc;
#pragma unroll
    for (int kb = 0; kb < 8; kb++) {
      bf16x8 a = *(const bf16x8*)&sW[kb][mr][quad * 8];
      const __hip_bfloat16* wp = wz_rad + ((size_t)(kb * 128 + n0 + mr) * 32 + quad * 8);
      bf16x8 b0 = *(const bf16x8*)wp;
      bf16x8 b1 = *(const bf16x8*)(wp + 16 * 32);
      acc0 = __builtin_amdgcn_mfma_f32_16x16x32_bf16(a, b0, acc0, 0, 0, 0);
      acc1 = __builtin_amdgcn_mfma_f32_16x16x32_bf16(a, b1, acc1, 0, 0, 0);
    }
    float bias0 = rad_b[n0 + mr], bias1 = rad_b[n0 + 16 + mr];
#pragma unroll
    for (int r = 0; r < 4; r++) {
      int e = quad * 4 + r;
      float inv = 1.f / s_rn[e];
      sA[8 + wave][e][mr]      = __float2bfloat16((acc0[r] + bias0) * inv);
      sA[8 + wave][e][16 + mr] = __float2bfloat16((acc1[r] + bias1) * inv);
    }
  }
  __syncthreads();
  // ---- stage 1: ef1 = silu(A @ e_w1 + e_b1), K=384 -> sT (=sW[0..3]) ----
  {
    f32x4 acc0 = zacc, acc1 = zacc;
#pragma unroll
    for (int kb = 0; kb < 12; kb++) {
      bf16x8 a = *(const bf16x8*)&sA[kb][mr][quad * 8];
      const __hip_bfloat16* wp = wz_e1 + ((size_t)(kb * 128 + n0 + mr) * 32 + quad * 8);
      bf16x8 b0 = *(const bf16x8*)wp;
      bf16x8 b1 = *(const bf16x8*)(wp + 16 * 32);
      acc0 = __builtin_amdgcn_mfma_f32_16x16x32_bf16(a, b0, acc0, 0, 0, 0);
      acc1 = __builtin_amdgcn_mfma_f32_16x16x32_bf16(a, b1, acc1, 0, 0, 0);
    }
    float bias0 = e_b1[n0 + mr], bias1 = e_b1[n0 + 16 + mr];
#pragma unroll
    for (int r = 0; r < 4; r++) {
      int e = quad * 4 + r;
      sW[wave][e][mr]      = __float2bfloat16(siluf(acc0[r] + bias0));
      sW[wave][e][16 + mr] = __float2bfloat16(siluf(acc1[r] + bias1));
    }
  }
  __syncthreads();
  // ---- stage 2: ef2 = silu(ef1 @ e_w2 + e_b2) -> sU (=sW[4..7]); gate partials ----
  {
    f32x4 acc0 = zacc, acc1 = zacc;
#pragma unroll
    for (int kb = 0; kb < 4; kb++) {
      bf16x8 a = *(const bf16x8*)&sW[kb][mr][quad * 8];
      const __hip_bfloat16* wp = wz_e2 + ((size_t)(kb * 128 + n0 + mr) * 32 + quad * 8);
      bf16x8 b0 = *(const bf16x8*)wp;
      bf16x8 b1 = *(const bf16x8*)(wp + 16 * 32);
      acc0 = __builtin_amdgcn_mfma_f32_16x16x32_bf16(a, b0, acc0, 0, 0, 0);
      acc1 = __builtin_amdgcn_mfma_f32_16x16x32_bf16(a, b1, acc1, 0, 0, 0);
    }
    float bias0 = e_b2[n0 + mr], bias1 = e_b2[n0 + 16 + mr];
#pragma unroll
    for (int r = 0; r < 4; r++) {
      int e = quad * 4 + r;
      float v0 = siluf(acc0[r] + bias0);
      float v1 = siluf(acc1[r] + bias1);
      sW[4 + wave][e][mr]      = __float2bfloat16(v0);
      sW[4 + wave][e][16 + mr] = __float2bfloat16(v1);
      s_red[e][wave * 16 + mr] = v0 * aw0 + v1 * aw1;   // gate partial dot
    }
  }
  __syncthreads();
  // ---- attention gate: sum partials ----
  {
    int e = t >> 4, p = t & 15;
    float s = s_red[e][p] + s_red[e][16 + p] + s_red[e][32 + p] + s_red[e][48 + p];
    s += __shfl_xor(s, 8); s += __shfl_xor(s, 4);
    s += __shfl_xor(s, 2); s += __shfl_xor(s, 1);
    if (p == 0) s_att[e] = sigmf(s + att_b0);
  }
  __syncthreads();
  // ---- stage 3: cmh = silu(att*(ef2 @ c_w1) + c_b1) -> sV (=sW[0..3]) ----
  {
    f32x4 acc0 = zacc, acc1 = zacc;
#pragma unroll
    for (int kb = 0; kb < 4; kb++) {
      bf16x8 a = *(const bf16x8*)&sW[4 + kb][mr][quad * 8];
      const __hip_bfloat16* wp = wz_c1 + ((size_t)(kb * 128 + n0 + mr) * 32 + quad * 8);
      bf16x8 b0 = *(const bf16x8*)wp;
      bf16x8 b1 = *(const bf16x8*)(wp + 16 * 32);
      acc0 = __builtin_amdgcn_mfma_f32_16x16x32_bf16(a, b0, acc0, 0, 0, 0);
      acc1 = __builtin_amdgcn_mfma_f32_16x16x32_bf16(a, b1, acc1, 0, 0, 0);
    }
    float bias0 = c_b1[n0 + mr], bias1 = c_b1[n0 + 16 + mr];
#pragma unroll
    for (int r = 0; r < 4; r++) {
      int e = quad * 4 + r;
      float av = s_att[e];
      sW[wave][e][mr]      = __float2bfloat16(siluf(av * acc0[r] + bias0));
      sW[wave][e][16 + mr] = __float2bfloat16(siluf(av * acc1[r] + bias1));
    }
  }
  __syncthreads();
  // ---- cm = cmh @ c_w2 + c_b2 via MFMA (wave 0 only) ----
  if (wave == 0) {
    f32x4 acc = zacc;
#pragma unroll
    for (int kb = 0; kb < 4; kb++) {
      bf16x8 a = *(const bf16x8*)&sW[kb][mr][quad * 8];
      bf16x8 b = *(const bf16x8*)(wz_c2 + ((size_t)(kb * 16 + mr) * 32 + quad * 8));
      acc = __builtin_amdgcn_mfma_f32_16x16x32_bf16(a, b, acc, 0, 0, 0);
    }
    if (mr < 14) {
      float bias = c_b2[mr];
#pragma unroll
      for (int r = 0; r < 4; r++) s_cm[quad * 4 + r][mr] = acc[r] + bias;
    }
  }
  __syncthreads();
  // ---- RollerPooling ----
  if (t < TE * 14) {
    int e = t / 14, c = t % 14;
    int wsz = 15 - s_cs[e];
    int hi = min(c + wsz, 14);
    float s = 0.f;
    for (int j = c; j < hi; j++) s += s_cm[e][j];
    s_pool[e][c] = s / (float)wsz;
  }
  __syncthreads();
  // ---- trans scatter (packed bf16 atomics) ----
  for (int i = t; i < TE * 21; i += 256) {
    int e = i / 21, pr = i % 21;
    if (e < ne) {
      int r0 = pr * 2, r1 = r0 + 1;
      float v0 = (s_xr[e][r0] - s_pc[e][r0 % 3]) * s_pool[e][r0 / 3];
      float v1 = (s_xr[e][r1] - s_pc[e][r1 % 3]) * s_pool[e][r1 / 3];
      unsafeAtomicAdd(&x_acc[(size_t)s_row[e] * 21 + pr], mk_bf162(v0, v1));
    }
  }
  // ---- agg scatter (gated ef2, packed bf16 atomics) ----
  for (int i = t; i < TE * 64; i += 256) {
    int e = i >> 6, o2 = i & 63;
    if (e < ne) {
      float av = s_att[e];
      const __hip_bfloat16* wp2 = &sW[4 + (o2 >> 4)][e][(o2 & 15) * 2];
      float v0 = __bfloat162float(wp2[0]) * av;
      float v1 = __bfloat162float(wp2[1]) * av;
      unsafeAtomicAdd(&agg[(size_t)s_col[e] * 64 + o2], mk_bf162(v0, v1));
    }
  }
}

// ---- node MLP (MFMA) + residual + LayerNorm + fused x_new ----
__global__ __launch_bounds__(256) void k_node(
    const float* __restrict__ h, const __hip_bfloat162* __restrict__ agg,
    const unsigned* __restrict__ cnt_col,
    const __hip_bfloat16* __restrict__ wz_n1, const float* __restrict__ n_b1,
    const __hip_bfloat16* __restrict__ wz_n2, const float* __restrict__ n_b2,
    const float* __restrict__ ln_g, const float* __restrict__ ln_b,
    const float* __restrict__ x, const __hip_bfloat162* __restrict__ x_acc,
    const unsigned* __restrict__ cnt_row,
    float* __restrict__ out_h, float* __restrict__ out_x, int Nn) {
  __shared__ __hip_bfloat16 sA[8][16][PAD];
  __shared__ __hip_bfloat16 sT[4][16][PAD];
  __shared__ float s_h[TN][128];
  __shared__ float s_o[TN][132];
  __shared__ float s_red[TN][16], s_mu[TN], s_rs[TN];
  const int t = threadIdx.x;
  const int nb0 = blockIdx.x * TN;
  const int nn = min(TN, Nn - nb0);

  // fused x_new
  for (int i = t; i < TN * 21; i += 256) {
    int n = i / 21, pr = i % 21;
    if (n < nn) {
      int gn = nb0 + n;
      unsigned c = cnt_row[gn];
      float inv = 1.f / (float)(c > 0 ? c : 1);
      float2 xa = __bfloat1622float2(x_acc[(size_t)gn * 21 + pr]);
      size_t gi = (size_t)gn * 42 + pr * 2;
      out_x[gi]     = x[gi] + xa.x * inv;
      out_x[gi + 1] = x[gi + 1] + xa.y * inv;
    }
  }

  for (int i = t; i < TN * 64; i += 256) {
    int m = i >> 6, kp = (i & 63) << 1;
    int kb = kp >> 5, kk = kp & 31;
    int gn = nb0 + min(m, nn - 1);
    const float2 hv = *(const float2*)&h[(size_t)gn * 128 + kp];
    sA[kb][m][kk]     = __float2bfloat16(hv.x);
    sA[kb][m][kk + 1] = __float2bfloat16(hv.y);
    s_h[m][kp]     = hv.x;
    s_h[m][kp + 1] = hv.y;
    unsigned c = cnt_col[gn];
    float inv = 1.f / (float)(c > 0 ? c : 1);
    float2 gv = __bfloat1622float2(agg[(size_t)gn * 64 + (kp >> 1)]);
    sA[4 + kb][m][kk]     = __float2bfloat16(gv.x * inv);
    sA[4 + kb][m][kk + 1] = __float2bfloat16(gv.y * inv);
  }
  __syncthreads();
  const int lane = t & 63, wave = t >> 6, quad = lane >> 4, mr = lane & 15;
  const int n0 = wave * 32;
  f32x4 zacc = {0.f, 0.f, 0.f, 0.f};
  {
    f32x4 acc0 = zacc, acc1 = zacc;
#pragma unroll
    for (int kb = 0; kb < 8; kb++) {
      bf16x8 a = *(const bf16x8*)&sA[kb][mr][quad * 8];
      const __hip_bfloat16* wp = wz_n1 + ((size_t)(kb * 128 + n0 + mr) * 32 + quad * 8);
      bf16x8 b0 = *(const bf16x8*)wp;
      bf16x8 b1 = *(const bf16x8*)(wp + 16 * 32);
      acc0 = __builtin_amdgcn_mfma_f32_16x16x32_bf16(a, b0, acc0, 0, 0, 0);
      acc1 = __builtin_amdgcn_mfma_f32_16x16x32_bf16(a, b1, acc1, 0, 0, 0);
    }
    float bias0 = n_b1[n0 + mr], bias1 = n_b1[n0 + 16 + mr];
#pragma unroll
    for (int r = 0; r < 4; r++) {
      int m = quad * 4 + r;
      sT[wave][m][mr]      = __float2bfloat16(siluf(acc0[r] + bias0));
      sT[wave][m][16 + mr] = __float2bfloat16(siluf(acc1[r] + bias1));
    }
  }
  __syncthreads();
  {
    f32x4 acc0 = zacc, acc1 = zacc;
#pragma unroll
    for (int kb = 0; kb < 4; kb++) {
      bf16x8 a = *(const bf16x8*)&sT[kb][mr][quad * 8];
      const __hip_bfloat16* wp = wz_n2 + ((size_t)(kb * 128 + n0 + mr) * 32 + quad * 8);
      bf16x8 b0 = *(const bf16x8*)wp;
      bf16x8 b1 = *(const bf16x8*)(wp + 16 * 32);
      acc0 = __builtin_amdgcn_mfma_f32_16x16x32_bf16(a, b0, acc0, 0, 0, 0);
      acc1 = __builtin_amdgcn_mfma_f32_16x16x32_bf16(a, b1, acc1, 0, 0, 0);
    }
    float bias0 = n_b2[n0 + mr], bias1 = n_b2[n0 + 16 + mr];
#pragma unroll
    for (int r = 0; r < 4; r++) {
      int m = quad * 4 + r;
      s_o[m][n0 + mr]      = s_h[m][n0 + mr] + acc0[r] + bias0;
      s_o[m][n0 + 16 + mr] = s_h[m][n0 + 16 + mr] + acc1[r] + bias1;
    }
  }
  __syncthreads();
  {
    int n = t >> 4, p = t & 15;
    float s = 0.f;
#pragma unroll
    for (int j = 0; j < 8; j++) s += s_o[n][p * 8 + j];
    s_red[n][p] = s;
  }
  __syncthreads();
  if (t < TN) {
    float s = 0.f;
#pragma unroll
    for (int i = 0; i < 16; i++) s += s_red[t][i];
    s_mu[t] = s * (1.f / 128.f);
  }
  __syncthreads();
  {
    int n = t >> 4, p = t & 15;
    float mu = s_mu[n], s = 0.f;
#pragma unroll
    for (int j = 0; j < 8; j++) {
      float d = s_o[n][p * 8 + j] - mu;
      s += d * d;
    }
    s_red[n][p] = s;
  }
  __syncthreads();
  if (t < TN) {
    float s = 0.f;
#pragma unroll
    for (int i = 0; i < 16; i++) s += s_red[t][i];
    s_rs[t] = rsqrtf(s * (1.f / 128.f) + 1e-5f);
  }
  __syncthreads();
  for (int i = t; i < TN * 128; i += 256) {
    int n = i >> 7, k = i & 127;
    if (n < nn)
      out_h[(size_t)(nb0 + n) * 128 + k] = (s_o[n][k] - s_mu[n]) * s_rs[n] * ln_g[k] + ln_b[k];
  }
}

extern "C" void kernel_launch(void* const* d_in, const int* in_sizes, int n_in,
                              void* d_out, int out_size, void* d_ws, size_t ws_size,
                              hipStream_t stream) {
  const float* h     = (const float*)d_in[0];
  const float* x     = (const float*)d_in[1];
  const float* attr  = (const float*)d_in[2];
  const float* cw    = (const float*)d_in[3];
  const int*   row   = (const int*)d_in[4];
  const int*   col   = (const int*)d_in[5];
  const float* rad_w = (const float*)d_in[6];
  const float* rad_b = (const float*)d_in[7];
  const float* e_w1  = (const float*)d_in[8];
  const float* e_b1  = (const float*)d_in[9];
  const float* e_w2  = (const float*)d_in[10];
  const float* e_b2  = (const float*)d_in[11];
  const float* att_w = (const float*)d_in[12];
  const float* att_b = (const float*)d_in[13];
  const float* c_w1  = (const float*)d_in[14];
  const float* c_b1  = (const float*)d_in[15];
  const float* c_w2  = (const float*)d_in[16];
  const float* c_b2  = (const float*)d_in[17];
  const float* n_w1  = (const float*)d_in[18];
  const float* n_b1  = (const float*)d_in[19];
  const float* n_w2  = (const float*)d_in[20];
  const float* n_b2  = (const float*)d_in[21];
  const float* ln_g  = (const float*)d_in[22];
  const float* ln_b  = (const float*)d_in[23];

  const int N = in_sizes[0] / 128;
  const int E = in_sizes[4];

  char* ws = (char*)d_ws;
  size_t off = 0;
  auto alloc = [&](size_t bytes) {
    size_t o = off;
    off += (bytes + 255) & ~(size_t)255;
    return o;
  };
  size_t off_wzr  = alloc(32768 * sizeof(__hip_bfloat16));
  size_t off_wz1  = alloc(49152 * sizeof(__hip_bfloat16));
  size_t off_wz2  = alloc(16384 * sizeof(__hip_bfloat16));
  size_t off_wzc  = alloc(16384 * sizeof(__hip_bfloat16));
  size_t off_wzn1 = alloc(32768 * sizeof(__hip_bfloat16));
  size_t off_wzn2 = alloc(16384 * sizeof(__hip_bfloat16));
  size_t off_wzc2 = alloc(2048 * sizeof(__hip_bfloat16));
  size_t off_atS  = alloc((size_t)N * 256 * sizeof(__hip_bfloat16));
  size_t off_hb   = alloc((size_t)N * 128 * sizeof(__hip_bfloat16));
  size_t off_px   = alloc((size_t)N * 3 * sizeof(float));
  size_t off_cs   = alloc((size_t)N * sizeof(int));
  size_t off_cntr = alloc((size_t)N * sizeof(unsigned));
  size_t off_cntc = alloc((size_t)N * sizeof(unsigned));
  size_t off_xacc = alloc((size_t)N * 21 * sizeof(__hip_bfloat162));
  size_t off_agg  = alloc((size_t)N * 64 * sizeof(__hip_bfloat162));

  __hip_bfloat16* wz_rad = (__hip_bfloat16*)(ws + off_wzr);
  __hip_bfloat16* wz_e1  = (__hip_bfloat16*)(ws + off_wz1);
  __hip_bfloat16* wz_e2  = (__hip_bfloat16*)(ws + off_wz2);
  __hip_bfloat16* wz_c1  = (__hip_bfloat16*)(ws + off_wzc);
  __hip_bfloat16* wz_n1  = (__hip_bfloat16*)(ws + off_wzn1);
  __hip_bfloat16* wz_n2  = (__hip_bfloat16*)(ws + off_wzn2);
  __hip_bfloat16* wz_c2  = (__hip_bfloat16*)(ws + off_wzc2);
  __hip_bfloat16* attrS  = (__hip_bfloat16*)(ws + off_atS);
  __hip_bfloat16* hb     = (__hip_bfloat16*)(ws + off_hb);
  float* pooled_x   = (float*)(ws + off_px);
  int* chsum        = (int*)(ws + off_cs);
  unsigned* cnt_row = (unsigned*)(ws + off_cntr);
  unsigned* cnt_col = (unsigned*)(ws + off_cntc);
  __hip_bfloat162* x_acc = (__hip_bfloat162*)(ws + off_xacc);
  __hip_bfloat162* agg   = (__hip_bfloat162*)(ws + off_agg);

  (void)hipMemsetAsync(ws + off_cntr, 0, off - off_cntr, stream);

  const int pack_items = 165888 + N * 256 + N * 128 + N;
  k_pack<<<dim3((pack_items + 255) / 256), dim3(256), 0, stream>>>(
      h, x, attr, cw, rad_w, e_w1, e_w2, c_w1, n_w1, n_w2, c_w2,
      wz_rad, wz_e1, wz_e2, wz_c1, wz_n1, wz_n2, wz_c2,
      attrS, hb, pooled_x, chsum, N);
  k_edge<<<dim3((E + TE - 1) / TE), dim3(256), 0, stream>>>(
      hb, x, attrS, row, col, pooled_x, chsum,
      wz_rad, rad_b, wz_e1, e_b1, wz_e2, e_b2, att_w, att_b,
      wz_c1, c_b1, wz_c2, c_b2, cnt_row, cnt_col, x_acc, agg, E);
  k_node<<<dim3((N + TN - 1) / TN), dim3(256), 0, stream>>>(
      h, agg, cnt_col, wz_n1, n_b1, wz_n2, n_b2, ln_g, ln_b,
      x, x_acc, cnt_row, (float*)d_out, (float*)d_out + (size_t)N * 128, N);
}

// Round 8
// 406.219 us; speedup vs baseline: 1.0362x; 1.0362x over previous
//
#include <hip/hip_runtime.h>
#include <hip/hip_bf16.h>

// EnhancedGNNEncoder round 8: latency-hiding round.
//  - LDS 34.8->30.8 KB (gate partials via in-quad shfl, s_red[4][16]) and
//    __launch_bounds__(256,5) -> 5 blocks/CU (was 3.5).
//  - All 4 einsum edges' gathers (x, attrS, indices) hoisted into registers
//    BEFORE the dependent MFMA chains: misses overlap instead of serializing.
//  - First block barrier removed: staging/einsum load row/col directly
//    (sequential -> L1-hot; wave-uniform in einsum -> s_load).
// MFMA 16x16x32: A[m=lane&15][k=quad*8+j], B[k=quad*8+j][n=lane&15],
//                D col=lane&15, row=quad*4+reg.

#define TE 16
#define TN 16
#define PAD 40

typedef __attribute__((ext_vector_type(8))) short bf16x8;
typedef __attribute__((ext_vector_type(4))) float f32x4;

__device__ __forceinline__ float siluf(float v) { return v / (1.f + __expf(-v)); }
__device__ __forceinline__ float sigmf(float v) { return 1.f / (1.f + __expf(-v)); }
__device__ __forceinline__ short f2bs(float f) {
  union { __hip_bfloat16 b; short s; } u;
  u.b = __float2bfloat16(f);
  return u.s;
}
__device__ __forceinline__ __hip_bfloat162 mk_bf162(float v0, float v1) {
  __hip_bfloat162 r;
  r.x = __float2bfloat16(v0);
  r.y = __float2bfloat16(v1);
  return r;
}

// ---- pack: weight swizzle + attrS + h_bf16 + per-node prep ----
__global__ __launch_bounds__(256) void k_pack(
    const float* __restrict__ h, const float* __restrict__ x,
    const float* __restrict__ attr, const float* __restrict__ cw,
    const float* __restrict__ rad_w, const float* __restrict__ e_w1,
    const float* __restrict__ e_w2, const float* __restrict__ c_w1,
    const float* __restrict__ n_w1, const float* __restrict__ n_w2,
    const float* __restrict__ c_w2,
    __hip_bfloat16* __restrict__ wz_rad, __hip_bfloat16* __restrict__ wz_e1,
    __hip_bfloat16* __restrict__ wz_e2, __hip_bfloat16* __restrict__ wz_c1,
    __hip_bfloat16* __restrict__ wz_n1, __hip_bfloat16* __restrict__ wz_n2,
    __hip_bfloat16* __restrict__ wz_c2,
    __hip_bfloat16* __restrict__ attrS, __hip_bfloat16* __restrict__ hb,
    float* __restrict__ pooled_x, int* __restrict__ chsum, int Nn) {
  int idx = blockIdx.x * 256 + threadIdx.x;
  if (idx < 165888) {  // weight swizzle
    int i = idx;
    if (i >= 163840) {  // c_w2: [128][14] -> [4][16][32], n=14,15 zero
      int base = i - 163840;
      int k = base >> 4, n = base & 15;
      wz_c2[(size_t)(k >> 5) * 512 + n * 32 + (k & 31)] =
          (n < 14) ? __float2bfloat16(c_w2[k * 14 + n]) : __float2bfloat16(0.f);
      return;
    }
    const float* W;
    __hip_bfloat16* O;
    int base;
    if (i < 32768) { W = rad_w; O = wz_rad; base = i; }
    else if (i < 81920) { W = e_w1; O = wz_e1; base = i - 32768; }
    else if (i < 98304) { W = e_w2; O = wz_e2; base = i - 81920; }
    else if (i < 114688) { W = c_w1; O = wz_c1; base = i - 98304; }
    else if (i < 147456) { W = n_w1; O = wz_n1; base = i - 114688; }
    else { W = n_w2; O = wz_n2; base = i - 147456; }
    int k = base >> 7, n = base & 127;
    O[(size_t)((k >> 5) * 128 + n) * 32 + (k & 31)] = __float2bfloat16(W[base]);
    return;
  }
  idx -= 165888;
  int na = Nn * 256, nh = Nn * 128;
  if (idx < na) {
    int n = idx >> 8, r = idx & 255, i2 = r >> 4, a = r & 15;
    float v = 0.f;
    if (i2 < 14) v = attr[(size_t)n * 224 + i2 * 16 + a] * cw[(size_t)n * 14 + i2];
    attrS[(size_t)n * 256 + a * 16 + i2] = __float2bfloat16(v);
    return;
  }
  idx -= na;
  if (idx < nh) {
    hb[idx] = __float2bfloat16(h[idx]);
    return;
  }
  idx -= nh;
  if (idx >= Nn) return;
  int n = idx;
  int cnt = 0;
  float sx = 0.f, sy = 0.f, sz = 0.f;
#pragma unroll
  for (int c = 0; c < 14; c++) {
    float w = cw[n * 14 + c];
    if (w != 0.f) {
      cnt++;
      sx += x[n * 42 + c * 3 + 0];
      sy += x[n * 42 + c * 3 + 1];
      sz += x[n * 42 + c * 3 + 2];
    }
  }
  chsum[n] = cnt;
  float inv = 1.f / (float)(cnt > 0 ? cnt : 1);
  pooled_x[n * 3 + 0] = sx * inv;
  pooled_x[n * 3 + 1] = sy * inv;
  pooled_x[n * 3 + 2] = sz * inv;
}

// ---- merged: radial einsum + rad GEMM + edge MLP + gate + roller + scatters ----
__global__ __launch_bounds__(256, 5) void k_edge(
    const __hip_bfloat16* __restrict__ hb, const float* __restrict__ x,
    const __hip_bfloat16* __restrict__ attrS,
    const int* __restrict__ row, const int* __restrict__ col,
    const float* __restrict__ pooled_x, const int* __restrict__ chsum,
    const __hip_bfloat16* __restrict__ wz_rad, const float* __restrict__ rad_b,
    const __hip_bfloat16* __restrict__ wz_e1, const float* __restrict__ e_b1,
    const __hip_bfloat16* __restrict__ wz_e2, const float* __restrict__ e_b2,
    const float* __restrict__ att_w, const float* __restrict__ att_b,
    const __hip_bfloat16* __restrict__ wz_c1, const float* __restrict__ c_b1,
    const __hip_bfloat16* __restrict__ wz_c2, const float* __restrict__ c_b2,
    unsigned* __restrict__ cnt_row, unsigned* __restrict__ cnt_col,
    __hip_bfloat162* __restrict__ x_acc, __hip_bfloat162* __restrict__ agg, int Ee) {
  __shared__ __hip_bfloat16 sA[12][16][PAD];  // [h_row | h_col | radf] K=384
  __shared__ __hip_bfloat16 sW[8][16][PAD];   // sRad / sT(0..3),sU(4..7),sV(0..3)
  __shared__ float s_xr[TE][42];
  __shared__ float s_pc[TE][3];
  __shared__ float s_cm[TE][14];
  __shared__ float s_pool[TE][14];
  __shared__ float s_red[4][16];
  __shared__ float s_att[TE], s_rn[TE];
  __shared__ int s_row[TE], s_col[TE], s_cs[TE];

  const int t = threadIdx.x;
  const int e0 = blockIdx.x * TE;
  const int ne = min(TE, Ee - e0);

  // index bookkeeping for the late phases (no barrier needed until roller/scatter)
  if (t < TE) {
    int e = e0 + min(t, ne - 1);
    int r = row[e], c = col[e];
    s_row[t] = r;
    s_col[t] = c;
    s_cs[t] = chsum[r];
    if (t < ne) {
      atomicAdd(&cnt_row[r], 1u);
      atomicAdd(&cnt_col[c], 1u);
    }
  }

  // h staging -> sA[0..7]: direct index loads (sequential row/col, L1-hot)
  for (int i = t; i < TE * 32; i += 256) {
    int half = i >> 8;
    int m = (i >> 4) & 15, c8 = i & 15;
    int kb = (c8 >> 2) + half * 4, kk = (c8 & 3) * 8;
    int ge = e0 + min(m, ne - 1);
    int node = half ? col[ge] : row[ge];
    *(int4*)&sA[kb][m][kk] = *(const int4*)&hb[(size_t)node * 128 + c8 * 8];
  }
  if (t < TE * 3) {
    int e = t / 3, d = t % 3;
    int ge = e0 + min(e, ne - 1);
    s_pc[e][d] = pooled_x[(size_t)col[ge] * 3 + d];
  }

  const int lane = t & 63, wave = t >> 6, quad = lane >> 4, mr = lane & 15;
  const int n0 = wave * 32;
  const float aw0 = att_w[n0 + mr], aw1 = att_w[n0 + 16 + mr];
  const float att_b0 = att_b[0];

  f32x4 zacc = {0.f, 0.f, 0.f, 0.f};
  const bf16x8 zero8 = {0, 0, 0, 0, 0, 0, 0, 0};

  // ---- einsum load phase: ALL 4 edges' gathers in flight before any chain ----
  float xr0v[4], xr1v[4], xr2v[4], xc0v[4], xc1v[4], xc2v[4];
  bf16x8 bCv[4], aRv[4];
#pragma unroll
  for (int p = 0; p < 4; p++) {
    const int e = wave * 4 + p;
    const int ge = e0 + min(e, ne - 1);
    const int re = row[ge], ce = col[ge];   // wave-uniform -> scalar loads
    const int mrc = min(mr, 13);
    const float* xp = x + (size_t)re * 42 + mrc * 3;
    xr0v[p] = xp[0]; xr1v[p] = xp[1]; xr2v[p] = xp[2];
    const float* xq = x + (size_t)ce * 42 + mrc * 3;
    xc0v[p] = xq[0]; xc1v[p] = xq[1]; xc2v[p] = xq[2];
    bCv[p] = zero8; aRv[p] = zero8;
    if (quad < 2) {
      bCv[p] = *(const bf16x8*)&attrS[(size_t)ce * 256 + mr * 16 + quad * 8];
      aRv[p] = *(const bf16x8*)&attrS[(size_t)re * 256 + mr * 16 + quad * 8];
    }
  }
#pragma unroll
  for (int p = 0; p < 4; p++) {
    const int e = wave * 4 + p;
    if (quad == 0 && mr < 14) {
      s_xr[e][mr * 3 + 0] = xr0v[p];
      s_xr[e][mr * 3 + 1] = xr1v[p];
      s_xr[e][mr * 3 + 2] = xr2v[p];
    }
  }

  // ---- einsum chains: each wave owns 4 edges ----
#pragma unroll
  for (int p = 0; p < 4; p++) {
    const int e = wave * 4 + p;
    const float xr0 = xr0v[p], xr1 = xr1v[p], xr2 = xr2v[p];
    const float xc0 = xc0v[p], xc1 = xc1v[p], xc2 = xc2v[p];
    // Gram cross-term: G[row=j][col=i] = xc_j . xr_i  (K=3, operands in-regs)
    bf16x8 aX = zero8, bX = zero8;
    if (quad == 0) {
      aX[0] = f2bs(xc0); aX[1] = f2bs(xc1); aX[2] = f2bs(xc2);
      bX[0] = f2bs(xr0); bX[1] = f2bs(xr1); bX[2] = f2bs(xr2);
    }
    f32x4 G = __builtin_amdgcn_mfma_f32_16x16x32_bf16(aX, bX, zacc, 0, 0, 0);
    const float nr = xr0 * xr0 + xr1 * xr1 + xr2 * xr2;
    const float nc = xc0 * xc0 + xc1 * xc1 + xc2 * xc2;
    float dD[4];
#pragma unroll
    for (int r = 0; r < 4; r++) {
      float ncj = __shfl(nc, quad * 4 + r);
      dD[r] = sqrtf(fmaxf(ncj + nr - 2.f * G[r], 0.f));
    }
    // transpose dists (D-layout) -> A-frag aD[m=i][k=j]
    bf16x8 aD;
#pragma unroll
    for (int jj = 0; jj < 8; jj++) {
      const int qs = (quad * 2 + (jj >> 2)) & 3;
      float dv = __shfl(dD[jj & 3], (qs << 4) | mr);
      if (quad >= 2) dv = 0.f;
      aD[jj] = f2bs(dv);
    }
    f32x4 m1 = __builtin_amdgcn_mfma_f32_16x16x32_bf16(aD, bCv[p], zacc, 0, 0, 0);
    bf16x8 bM;
#pragma unroll
    for (int jj = 0; jj < 8; jj++) {
      const int qs = (quad * 2 + (jj >> 2)) & 3;
      float mv = __shfl(m1[jj & 3], (qs << 4) | mr);
      if (quad >= 2) mv = 0.f;
      bM[jj] = f2bs(mv);
    }
    f32x4 rd = __builtin_amdgcn_mfma_f32_16x16x32_bf16(aRv[p], bM, zacc, 0, 0, 0);
    float ss = rd[0] * rd[0] + rd[1] * rd[1] + rd[2] * rd[2] + rd[3] * rd[3];
    ss += __shfl_xor(ss, 32); ss += __shfl_xor(ss, 16); ss += __shfl_xor(ss, 8);
    ss += __shfl_xor(ss, 4);  ss += __shfl_xor(ss, 2);  ss += __shfl_xor(ss, 1);
    if (lane == 0) s_rn[e] = sqrtf(ss) + 1.0f;
#pragma unroll
    for (int r = 0; r < 4; r++) {
      const int aa = quad * 4 + r;
      sW[aa >> 1][e][((aa & 1) << 4) | mr] = __float2bfloat16(rd[r]);
    }
  }
  __syncthreads();

  // ---- rad GEMM: radf = (radial @ rad_w + rad_b)/rn -> sA[8..11] ----
  {
    f32x4 acc0 = zacc, acc1 = zacc;
#pragma unroll
    for (int kb = 0; kb < 8; kb++) {
      bf16x8 a = *(const bf16x8*)&sW[kb][mr][quad * 8];
      const __hip_bfloat16* wp = wz_rad + ((size_t)(kb * 128 + n0 + mr) * 32 + quad * 8);
      bf16x8 b0 = *(const bf16x8*)wp;
      bf16x8 b1 = *(const bf16x8*)(wp + 16 * 32);
      acc0 = __builtin_amdgcn_mfma_f32_16x16x32_bf16(a, b0, acc0, 0, 0, 0);
      acc1 = __builtin_amdgcn_mfma_f32_16x16x32_bf16(a, b1, acc1, 0, 0, 0);
    }
    float bias0 = rad_b[n0 + mr], bias1 = rad_b[n0 + 16 + mr];
#pragma unroll
    for (int r = 0; r < 4; r++) {
      int e = quad * 4 + r;
      float inv = 1.f / s_rn[e];
      sA[8 + wave][e][mr]      = __float2bfloat16((acc0[r] + bias0) * inv);
      sA[8 + wave][e][16 + mr] = __float2bfloat16((acc1[r] + bias1) * inv);
    }
  }
  __syncthreads();
  // ---- stage 1: ef1 = silu(A @ e_w1 + e_b1), K=384 -> sT (=sW[0..3]) ----
  {
    f32x4 acc0 = zacc, acc1 = zacc;
#pragma unroll
    for (int kb = 0; kb < 12; kb++) {
      bf16x8 a = *(const bf16x8*)&sA[kb][mr][quad * 8];
      const __hip_bfloat16* wp = wz_e1 + ((size_t)(kb * 128 + n0 + mr) * 32 + quad * 8);
      bf16x8 b0 = *(const bf16x8*)wp;
      bf16x8 b1 = *(const bf16x8*)(wp + 16 * 32);
      acc0 = __builtin_amdgcn_mfma_f32_16x16x32_bf16(a, b0, acc0, 0, 0, 0);
      acc1 = __builtin_amdgcn_mfma_f32_16x16x32_bf16(a, b1, acc1, 0, 0, 0);
    }
    float bias0 = e_b1[n0 + mr], bias1 = e_b1[n0 + 16 + mr];
#pragma unroll
    for (int r = 0; r < 4; r++) {
      int e = quad * 4 + r;
      sW[wave][e][mr]      = __float2bfloat16(siluf(acc0[r] + bias0));
      sW[wave][e][16 + mr] = __float2bfloat16(siluf(acc1[r] + bias1));
    }
  }
  __syncthreads();
  // ---- stage 2: ef2 = silu(ef1 @ e_w2 + e_b2) -> sU (=sW[4..7]); gate partials ----
  {
    f32x4 acc0 = zacc, acc1 = zacc;
#pragma unroll
    for (int kb = 0; kb < 4; kb++) {
      bf16x8 a = *(const bf16x8*)&sW[kb][mr][quad * 8];
      const __hip_bfloat16* wp = wz_e2 + ((size_t)(kb * 128 + n0 + mr) * 32 + quad * 8);
      bf16x8 b0 = *(const bf16x8*)wp;
      bf16x8 b1 = *(const bf16x8*)(wp + 16 * 32);
      acc0 = __builtin_amdgcn_mfma_f32_16x16x32_bf16(a, b0, acc0, 0, 0, 0);
      acc1 = __builtin_amdgcn_mfma_f32_16x16x32_bf16(a, b1, acc1, 0, 0, 0);
    }
    float bias0 = e_b2[n0 + mr], bias1 = e_b2[n0 + 16 + mr];
    float part[4];
#pragma unroll
    for (int r = 0; r < 4; r++) {
      int e = quad * 4 + r;
      float v0 = siluf(acc0[r] + bias0);
      float v1 = siluf(acc1[r] + bias1);
      sW[4 + wave][e][mr]      = __float2bfloat16(v0);
      sW[4 + wave][e][16 + mr] = __float2bfloat16(v1);
      part[r] = v0 * aw0 + v1 * aw1;
    }
    // in-quad reduce over mr (16 lanes): lanes q*16+mr, xor masks 1,2,4,8
#pragma unroll
    for (int msk = 1; msk < 16; msk <<= 1) {
#pragma unroll
      for (int r = 0; r < 4; r++) part[r] += __shfl_xor(part[r], msk);
    }
    if (mr == 0) {
#pragma unroll
      for (int r = 0; r < 4; r++) s_red[wave][quad * 4 + r] = part[r];
    }
  }
  __syncthreads();
  // ---- attention gate: sum the 4 wave-partials ----
  if (t < TE) {
    float s = s_red[0][t] + s_red[1][t] + s_red[2][t] + s_red[3][t];
    s_att[t] = sigmf(s + att_b0);
  }
  __syncthreads();
  // ---- stage 3: cmh = silu(att*(ef2 @ c_w1) + c_b1) -> sV (=sW[0..3]) ----
  {
    f32x4 acc0 = zacc, acc1 = zacc;
#pragma unroll
    for (int kb = 0; kb < 4; kb++) {
      bf16x8 a = *(const bf16x8*)&sW[4 + kb][mr][quad * 8];
      const __hip_bfloat16* wp = wz_c1 + ((size_t)(kb * 128 + n0 + mr) * 32 + quad * 8);
      bf16x8 b0 = *(const bf16x8*)wp;
      bf16x8 b1 = *(const bf16x8*)(wp + 16 * 32);
      acc0 = __builtin_amdgcn_mfma_f32_16x16x32_bf16(a, b0, acc0, 0, 0, 0);
      acc1 = __builtin_amdgcn_mfma_f32_16x16x32_bf16(a, b1, acc1, 0, 0, 0);
    }
    float bias0 = c_b1[n0 + mr], bias1 = c_b1[n0 + 16 + mr];
#pragma unroll
    for (int r = 0; r < 4; r++) {
      int e = quad * 4 + r;
      float av = s_att[e];
      sW[wave][e][mr]      = __float2bfloat16(siluf(av * acc0[r] + bias0));
      sW[wave][e][16 + mr] = __float2bfloat16(siluf(av * acc1[r] + bias1));
    }
  }
  __syncthreads();
  // ---- cm = cmh @ c_w2 + c_b2 via MFMA (wave 0 only) ----
  if (wave == 0) {
    f32x4 acc = zacc;
#pragma unroll
    for (int kb = 0; kb < 4; kb++) {
      bf16x8 a = *(const bf16x8*)&sW[kb][mr][quad * 8];
      bf16x8 b = *(const bf16x8*)(wz_c2 + ((size_t)(kb * 16 + mr) * 32 + quad * 8));
      acc = __builtin_amdgcn_mfma_f32_16x16x32_bf16(a, b, acc, 0, 0, 0);
    }
    if (mr < 14) {
      float bias = c_b2[mr];
#pragma unroll
      for (int r = 0; r < 4; r++) s_cm[quad * 4 + r][mr] = acc[r] + bias;
    }
  }
  __syncthreads();
  // ---- RollerPooling ----
  if (t < TE * 14) {
    int e = t / 14, c = t % 14;
    int wsz = 15 - s_cs[e];
    int hi = min(c + wsz, 14);
    float s = 0.f;
    for (int j = c; j < hi; j++) s += s_cm[e][j];
    s_pool[e][c] = s / (float)wsz;
  }
  __syncthreads();
  // ---- trans scatter (packed bf16 atomics) ----
  for (int i = t; i < TE * 21; i += 256) {
    int e = i / 21, pr = i % 21;
    if (e < ne) {
      int r0 = pr * 2, r1 = r0 + 1;
      float v0 = (s_xr[e][r0] - s_pc[e][r0 % 3]) * s_pool[e][r0 / 3];
      float v1 = (s_xr[e][r1] - s_pc[e][r1 % 3]) * s_pool[e][r1 / 3];
      unsafeAtomicAdd(&x_acc[(size_t)s_row[e] * 21 + pr], mk_bf162(v0, v1));
    }
  }
  // ---- agg scatter (gated ef2, packed bf16 atomics) ----
  for (int i = t; i < TE * 64; i += 256) {
    int e = i >> 6, o2 = i & 63;
    if (e < ne) {
      float av = s_att[e];
      const __hip_bfloat16* wp2 = &sW[4 + (o2 >> 4)][e][(o2 & 15) * 2];
      float v0 = __bfloat162float(wp2[0]) * av;
      float v1 = __bfloat162float(wp2[1]) * av;
      unsafeAtomicAdd(&agg[(size_t)s_col[e] * 64 + o2], mk_bf162(v0, v1));
    }
  }
}

// ---- node MLP (MFMA) + residual + LayerNorm + fused x_new ----
__global__ __launch_bounds__(256) void k_node(
    const float* __restrict__ h, const __hip_bfloat162* __restrict__ agg,
    const unsigned* __restrict__ cnt_col,
    const __hip_bfloat16* __restrict__ wz_n1, const float* __restrict__ n_b1,
    const __hip_bfloat16* __restrict__ wz_n2, const float* __restrict__ n_b2,
    const float* __restrict__ ln_g, const float* __restrict__ ln_b,
    const float* __restrict__ x, const __hip_bfloat162* __restrict__ x_acc,
    const unsigned* __restrict__ cnt_row,
    float* __restrict__ out_h, float* __restrict__ out_x, int Nn) {
  __shared__ __hip_bfloat16 sA[8][16][PAD];
  __shared__ __hip_bfloat16 sT[4][16][PAD];
  __shared__ float s_h[TN][128];
  __shared__ float s_o[TN][132];
  __shared__ float s_red[TN][16], s_mu[TN], s_rs[TN];
  const int t = threadIdx.x;
  const int nb0 = blockIdx.x * TN;
  const int nn = min(TN, Nn - nb0);

  // fused x_new
  for (int i = t; i < TN * 21; i += 256) {
    int n = i / 21, pr = i % 21;
    if (n < nn) {
      int gn = nb0 + n;
      unsigned c = cnt_row[gn];
      float inv = 1.f / (float)(c > 0 ? c : 1);
      float2 xa = __bfloat1622float2(x_acc[(size_t)gn * 21 + pr]);
      size_t gi = (size_t)gn * 42 + pr * 2;
      out_x[gi]     = x[gi] + xa.x * inv;
      out_x[gi + 1] = x[gi + 1] + xa.y * inv;
    }
  }

  for (int i = t; i < TN * 64; i += 256) {
    int m = i >> 6, kp = (i & 63) << 1;
    int kb = kp >> 5, kk = kp & 31;
    int gn = nb0 + min(m, nn - 1);
    const float2 hv = *(const float2*)&h[(size_t)gn * 128 + kp];
    sA[kb][m][kk]     = __float2bfloat16(hv.x);
    sA[kb][m][kk + 1] = __float2bfloat16(hv.y);
    s_h[m][kp]     = hv.x;
    s_h[m][kp + 1] = hv.y;
    unsigned c = cnt_col[gn];
    float inv = 1.f / (float)(c > 0 ? c : 1);
    float2 gv = __bfloat1622float2(agg[(size_t)gn * 64 + (kp >> 1)]);
    sA[4 + kb][m][kk]     = __float2bfloat16(gv.x * inv);
    sA[4 + kb][m][kk + 1] = __float2bfloat16(gv.y * inv);
  }
  __syncthreads();
  const int lane = t & 63, wave = t >> 6, quad = lane >> 4, mr = lane & 15;
  const int n0 = wave * 32;
  f32x4 zacc = {0.f, 0.f, 0.f, 0.f};
  {
    f32x4 acc0 = zacc, acc1 = zacc;
#pragma unroll
    for (int kb = 0; kb < 8; kb++) {
      bf16x8 a = *(const bf16x8*)&sA[kb][mr][quad * 8];
      const __hip_bfloat16* wp = wz_n1 + ((size_t)(kb * 128 + n0 + mr) * 32 + quad * 8);
      bf16x8 b0 = *(const bf16x8*)wp;
      bf16x8 b1 = *(const bf16x8*)(wp + 16 * 32);
      acc0 = __builtin_amdgcn_mfma_f32_16x16x32_bf16(a, b0, acc0, 0, 0, 0);
      acc1 = __builtin_amdgcn_mfma_f32_16x16x32_bf16(a, b1, acc1, 0, 0, 0);
    }
    float bias0 = n_b1[n0 + mr], bias1 = n_b1[n0 + 16 + mr];
#pragma unroll
    for (int r = 0; r < 4; r++) {
      int m = quad * 4 + r;
      sT[wave][m][mr]      = __float2bfloat16(siluf(acc0[r] + bias0));
      sT[wave][m][16 + mr] = __float2bfloat16(siluf(acc1[r] + bias1));
    }
  }
  __syncthreads();
  {
    f32x4 acc0 = zacc, acc1 = zacc;
#pragma unroll
    for (int kb = 0; kb < 4; kb++) {
      bf16x8 a = *(const bf16x8*)&sT[kb][mr][quad * 8];
      const __hip_bfloat16* wp = wz_n2 + ((size_t)(kb * 128 + n0 + mr) * 32 + quad * 8);
      bf16x8 b0 = *(const bf16x8*)wp;
      bf16x8 b1 = *(const bf16x8*)(wp + 16 * 32);
      acc0 = __builtin_amdgcn_mfma_f32_16x16x32_bf16(a, b0, acc0, 0, 0, 0);
      acc1 = __builtin_amdgcn_mfma_f32_16x16x32_bf16(a, b1, acc1, 0, 0, 0);
    }
    float bias0 = n_b2[n0 + mr], bias1 = n_b2[n0 + 16 + mr];
#pragma unroll
    for (int r = 0; r < 4; r++) {
      int m = quad * 4 + r;
      s_o[m][n0 + mr]      = s_h[m][n0 + mr] + acc0[r] + bias0;
      s_o[m][n0 + 16 + mr] = s_h[m][n0 + 16 + mr] + acc1[r] + bias1;
    }
  }
  __syncthreads();
  {
    int n = t >> 4, p = t & 15;
    float s = 0.f;
#pragma unroll
    for (int j = 0; j < 8; j++) s += s_o[n][p * 8 + j];
    s_red[n][p] = s;
  }
  __syncthreads();
  if (t < TN) {
    float s = 0.f;
#pragma unroll
    for (int i = 0; i < 16; i++) s += s_red[t][i];
    s_mu[t] = s * (1.f / 128.f);
  }
  __syncthreads();
  {
    int n = t >> 4, p = t & 15;
    float mu = s_mu[n], s = 0.f;
#pragma unroll
    for (int j = 0; j < 8; j++) {
      float d = s_o[n][p * 8 + j] - mu;
      s += d * d;
    }
    s_red[n][p] = s;
  }
  __syncthreads();
  if (t < TN) {
    float s = 0.f;
#pragma unroll
    for (int i = 0; i < 16; i++) s += s_red[t][i];
    s_rs[t] = rsqrtf(s * (1.f / 128.f) + 1e-5f);
  }
  __syncthreads();
  for (int i = t; i < TN * 128; i += 256) {
    int n = i >> 7, k = i & 127;
    if (n < nn)
      out_h[(size_t)(nb0 + n) * 128 + k] = (s_o[n][k] - s_mu[n]) * s_rs[n] * ln_g[k] + ln_b[k];
  }
}

extern "C" void kernel_launch(void* const* d_in, const int* in_sizes, int n_in,
                              void* d_out, int out_size, void* d_ws, size_t ws_size,
                              hipStream_t stream) {
  const float* h     = (const float*)d_in[0];
  const float* x     = (const float*)d_in[1];
  const float* attr  = (const float*)d_in[2];
  const float* cw    = (const float*)d_in[3];
  const int*   row   = (const int*)d_in[4];
  const int*   col   = (const int*)d_in[5];
  const float* rad_w = (const float*)d_in[6];
  const float* rad_b = (const float*)d_in[7];
  const float* e_w1  = (const float*)d_in[8];
  const float* e_b1  = (const float*)d_in[9];
  const float* e_w2  = (const float*)d_in[10];
  const float* e_b2  = (const float*)d_in[11];
  const float* att_w = (const float*)d_in[12];
  const float* att_b = (const float*)d_in[13];
  const float* c_w1  = (const float*)d_in[14];
  const float* c_b1  = (const float*)d_in[15];
  const float* c_w2  = (const float*)d_in[16];
  const float* c_b2  = (const float*)d_in[17];
  const float* n_w1  = (const float*)d_in[18];
  const float* n_b1  = (const float*)d_in[19];
  const float* n_w2  = (const float*)d_in[20];
  const float* n_b2  = (const float*)d_in[21];
  const float* ln_g  = (const float*)d_in[22];
  const float* ln_b  = (const float*)d_in[23];

  const int N = in_sizes[0] / 128;
  const int E = in_sizes[4];

  char* ws = (char*)d_ws;
  size_t off = 0;
  auto alloc = [&](size_t bytes) {
    size_t o = off;
    off += (bytes + 255) & ~(size_t)255;
    return o;
  };
  size_t off_wzr  = alloc(32768 * sizeof(__hip_bfloat16));
  size_t off_wz1  = alloc(49152 * sizeof(__hip_bfloat16));
  size_t off_wz2  = alloc(16384 * sizeof(__hip_bfloat16));
  size_t off_wzc  = alloc(16384 * sizeof(__hip_bfloat16));
  size_t off_wzn1 = alloc(32768 * sizeof(__hip_bfloat16));
  size_t off_wzn2 = alloc(16384 * sizeof(__hip_bfloat16));
  size_t off_wzc2 = alloc(2048 * sizeof(__hip_bfloat16));
  size_t off_atS  = alloc((size_t)N * 256 * sizeof(__hip_bfloat16));
  size_t off_hb   = alloc((size_t)N * 128 * sizeof(__hip_bfloat16));
  size_t off_px   = alloc((size_t)N * 3 * sizeof(float));
  size_t off_cs   = alloc((size_t)N * sizeof(int));
  size_t off_cntr = alloc((size_t)N * sizeof(unsigned));
  size_t off_cntc = alloc((size_t)N * sizeof(unsigned));
  size_t off_xacc = alloc((size_t)N * 21 * sizeof(__hip_bfloat162));
  size_t off_agg  = alloc((size_t)N * 64 * sizeof(__hip_bfloat162));

  __hip_bfloat16* wz_rad = (__hip_bfloat16*)(ws + off_wzr);
  __hip_bfloat16* wz_e1  = (__hip_bfloat16*)(ws + off_wz1);
  __hip_bfloat16* wz_e2  = (__hip_bfloat16*)(ws + off_wz2);
  __hip_bfloat16* wz_c1  = (__hip_bfloat16*)(ws + off_wzc);
  __hip_bfloat16* wz_n1  = (__hip_bfloat16*)(ws + off_wzn1);
  __hip_bfloat16* wz_n2  = (__hip_bfloat16*)(ws + off_wzn2);
  __hip_bfloat16* wz_c2  = (__hip_bfloat16*)(ws + off_wzc2);
  __hip_bfloat16* attrS  = (__hip_bfloat16*)(ws + off_atS);
  __hip_bfloat16* hb     = (__hip_bfloat16*)(ws + off_hb);
  float* pooled_x   = (float*)(ws + off_px);
  int* chsum        = (int*)(ws + off_cs);
  unsigned* cnt_row = (unsigned*)(ws + off_cntr);
  unsigned* cnt_col = (unsigned*)(ws + off_cntc);
  __hip_bfloat162* x_acc = (__hip_bfloat162*)(ws + off_xacc);
  __hip_bfloat162* agg   = (__hip_bfloat162*)(ws + off_agg);

  (void)hipMemsetAsync(ws + off_cntr, 0, off - off_cntr, stream);

  const int pack_items = 165888 + N * 256 + N * 128 + N;
  k_pack<<<dim3((pack_items + 255) / 256), dim3(256), 0, stream>>>(
      h, x, attr, cw, rad_w, e_w1, e_w2, c_w1, n_w1, n_w2, c_w2,
      wz_rad, wz_e1, wz_e2, wz_c1, wz_n1, wz_n2, wz_c2,
      attrS, hb, pooled_x, chsum, N);
  k_edge<<<dim3((E + TE - 1) / TE), dim3(256), 0, stream>>>(
      hb, x, attrS, row, col, pooled_x, chsum,
      wz_rad, rad_b, wz_e1, e_b1, wz_e2, e_b2, att_w, att_b,
      wz_c1, c_b1, wz_c2, c_b2, cnt_row, cnt_col, x_acc, agg, E);
  k_node<<<dim3((N + TN - 1) / TN), dim3(256), 0, stream>>>(
      h, agg, cnt_col, wz_n1, n_b1, wz_n2, n_b2, ln_g, ln_b,
      x, x_acc, cnt_row, (float*)d_out, (float*)d_out + (size_t)N * 128, N);
}

// Round 9
// 391.901 us; speedup vs baseline: 1.0741x; 1.0365x over previous
//
#include <hip/hip_runtime.h>
#include <hip/hip_bf16.h>

// EnhancedGNNEncoder round 9: occupancy push + tail cleanup.
//  - k_edge LDS 31.2->26.2 KB: PAD 40->36 (72B rows; b128 frag reads are
//    exactly bank-balanced) + s_cm/s_pool/s_red/s_att aliased onto sA (dead
//    after stage 1) -> __launch_bounds__(256,6) = 6 blocks/CU (was 5).
//  - k_node LayerNorm fully in-wave (node's 16 threads are contiguous lanes):
//    mean/var via shfl_xor, row values in registers -> 4 barriers removed.
// MFMA 16x16x32: A[m=lane&15][k=quad*8+j], B[k=quad*8+j][n=lane&15],
//                D col=lane&15, row=quad*4+reg.

#define TE 16
#define TN 16
#define PAD 36

typedef __attribute__((ext_vector_type(8))) short bf16x8;
typedef __attribute__((ext_vector_type(4))) float f32x4;

__device__ __forceinline__ float siluf(float v) { return v / (1.f + __expf(-v)); }
__device__ __forceinline__ float sigmf(float v) { return 1.f / (1.f + __expf(-v)); }
__device__ __forceinline__ short f2bs(float f) {
  union { __hip_bfloat16 b; short s; } u;
  u.b = __float2bfloat16(f);
  return u.s;
}
__device__ __forceinline__ __hip_bfloat162 mk_bf162(float v0, float v1) {
  __hip_bfloat162 r;
  r.x = __float2bfloat16(v0);
  r.y = __float2bfloat16(v1);
  return r;
}

// ---- pack: weight swizzle + attrS + h_bf16 + per-node prep ----
__global__ __launch_bounds__(256) void k_pack(
    const float* __restrict__ h, const float* __restrict__ x,
    const float* __restrict__ attr, const float* __restrict__ cw,
    const float* __restrict__ rad_w, const float* __restrict__ e_w1,
    const float* __restrict__ e_w2, const float* __restrict__ c_w1,
    const float* __restrict__ n_w1, const float* __restrict__ n_w2,
    const float* __restrict__ c_w2,
    __hip_bfloat16* __restrict__ wz_rad, __hip_bfloat16* __restrict__ wz_e1,
    __hip_bfloat16* __restrict__ wz_e2, __hip_bfloat16* __restrict__ wz_c1,
    __hip_bfloat16* __restrict__ wz_n1, __hip_bfloat16* __restrict__ wz_n2,
    __hip_bfloat16* __restrict__ wz_c2,
    __hip_bfloat16* __restrict__ attrS, __hip_bfloat16* __restrict__ hb,
    float* __restrict__ pooled_x, int* __restrict__ chsum, int Nn) {
  int idx = blockIdx.x * 256 + threadIdx.x;
  if (idx < 165888) {  // weight swizzle
    int i = idx;
    if (i >= 163840) {  // c_w2: [128][14] -> [4][16][32], n=14,15 zero
      int base = i - 163840;
      int k = base >> 4, n = base & 15;
      wz_c2[(size_t)(k >> 5) * 512 + n * 32 + (k & 31)] =
          (n < 14) ? __float2bfloat16(c_w2[k * 14 + n]) : __float2bfloat16(0.f);
      return;
    }
    const float* W;
    __hip_bfloat16* O;
    int base;
    if (i < 32768) { W = rad_w; O = wz_rad; base = i; }
    else if (i < 81920) { W = e_w1; O = wz_e1; base = i - 32768; }
    else if (i < 98304) { W = e_w2; O = wz_e2; base = i - 81920; }
    else if (i < 114688) { W = c_w1; O = wz_c1; base = i - 98304; }
    else if (i < 147456) { W = n_w1; O = wz_n1; base = i - 114688; }
    else { W = n_w2; O = wz_n2; base = i - 147456; }
    int k = base >> 7, n = base & 127;
    O[(size_t)((k >> 5) * 128 + n) * 32 + (k & 31)] = __float2bfloat16(W[base]);
    return;
  }
  idx -= 165888;
  int na = Nn * 256, nh = Nn * 128;
  if (idx < na) {
    int n = idx >> 8, r = idx & 255, i2 = r >> 4, a = r & 15;
    float v = 0.f;
    if (i2 < 14) v = attr[(size_t)n * 224 + i2 * 16 + a] * cw[(size_t)n * 14 + i2];
    attrS[(size_t)n * 256 + a * 16 + i2] = __float2bfloat16(v);
    return;
  }
  idx -= na;
  if (idx < nh) {
    hb[idx] = __float2bfloat16(h[idx]);
    return;
  }
  idx -= nh;
  if (idx >= Nn) return;
  int n = idx;
  int cnt = 0;
  float sx = 0.f, sy = 0.f, sz = 0.f;
#pragma unroll
  for (int c = 0; c < 14; c++) {
    float w = cw[n * 14 + c];
    if (w != 0.f) {
      cnt++;
      sx += x[n * 42 + c * 3 + 0];
      sy += x[n * 42 + c * 3 + 1];
      sz += x[n * 42 + c * 3 + 2];
    }
  }
  chsum[n] = cnt;
  float inv = 1.f / (float)(cnt > 0 ? cnt : 1);
  pooled_x[n * 3 + 0] = sx * inv;
  pooled_x[n * 3 + 1] = sy * inv;
  pooled_x[n * 3 + 2] = sz * inv;
}

// ---- merged: radial einsum + rad GEMM + edge MLP + gate + roller + scatters ----
__global__ __launch_bounds__(256, 6) void k_edge(
    const __hip_bfloat16* __restrict__ hb, const float* __restrict__ x,
    const __hip_bfloat16* __restrict__ attrS,
    const int* __restrict__ row, const int* __restrict__ col,
    const float* __restrict__ pooled_x, const int* __restrict__ chsum,
    const __hip_bfloat16* __restrict__ wz_rad, const float* __restrict__ rad_b,
    const __hip_bfloat16* __restrict__ wz_e1, const float* __restrict__ e_b1,
    const __hip_bfloat16* __restrict__ wz_e2, const float* __restrict__ e_b2,
    const float* __restrict__ att_w, const float* __restrict__ att_b,
    const __hip_bfloat16* __restrict__ wz_c1, const float* __restrict__ c_b1,
    const __hip_bfloat16* __restrict__ wz_c2, const float* __restrict__ c_b2,
    unsigned* __restrict__ cnt_row, unsigned* __restrict__ cnt_col,
    __hip_bfloat162* __restrict__ x_acc, __hip_bfloat162* __restrict__ agg, int Ee) {
  __shared__ __hip_bfloat16 sA[12][16][PAD];  // [h_row | h_col | radf] K=384
  __shared__ __hip_bfloat16 sW[8][16][PAD];   // sRad / sT(0..3),sU(4..7),sV(0..3)
  __shared__ float s_xr[TE][42];
  __shared__ float s_pc[TE][3];
  __shared__ float s_rn[TE];
  __shared__ int s_row[TE], s_col[TE], s_cs[TE];
  // aliased onto sA (sA is dead after stage 1; these are written after it):
  float* s_cm   = (float*)&sA[0][0][0];   // [16*14]
  float* s_pool = s_cm + 224;             // [16*14]
  float* s_red4 = s_pool + 224;           // [4*16]
  float* s_att  = s_red4 + 64;            // [16]

  const int t = threadIdx.x;
  const int e0 = blockIdx.x * TE;
  const int ne = min(TE, Ee - e0);

  if (t < TE) {
    int e = e0 + min(t, ne - 1);
    int r = row[e], c = col[e];
    s_row[t] = r;
    s_col[t] = c;
    s_cs[t] = chsum[r];
    if (t < ne) {
      atomicAdd(&cnt_row[r], 1u);
      atomicAdd(&cnt_col[c], 1u);
    }
  }

  // h staging -> sA[0..7]: direct index loads (sequential row/col, L1-hot)
  for (int i = t; i < TE * 32; i += 256) {
    int half = i >> 8;
    int m = (i >> 4) & 15, c8 = i & 15;
    int kb = (c8 >> 2) + half * 4, kk = (c8 & 3) * 8;
    int ge = e0 + min(m, ne - 1);
    int node = half ? col[ge] : row[ge];
    *(int4*)&sA[kb][m][kk] = *(const int4*)&hb[(size_t)node * 128 + c8 * 8];
  }
  if (t < TE * 3) {
    int e = t / 3, d = t % 3;
    int ge = e0 + min(e, ne - 1);
    s_pc[e][d] = pooled_x[(size_t)col[ge] * 3 + d];
  }

  const int lane = t & 63, wave = t >> 6, quad = lane >> 4, mr = lane & 15;
  const int n0 = wave * 32;
  const float aw0 = att_w[n0 + mr], aw1 = att_w[n0 + 16 + mr];
  const float att_b0 = att_b[0];

  f32x4 zacc = {0.f, 0.f, 0.f, 0.f};
  const bf16x8 zero8 = {0, 0, 0, 0, 0, 0, 0, 0};

  // ---- einsum load phase: ALL 4 edges' gathers in flight before any chain ----
  float xr0v[4], xr1v[4], xr2v[4], xc0v[4], xc1v[4], xc2v[4];
  bf16x8 bCv[4], aRv[4];
#pragma unroll
  for (int p = 0; p < 4; p++) {
    const int e = wave * 4 + p;
    const int ge = e0 + min(e, ne - 1);
    const int re = row[ge], ce = col[ge];   // wave-uniform -> scalar loads
    const int mrc = min(mr, 13);
    const float* xp = x + (size_t)re * 42 + mrc * 3;
    xr0v[p] = xp[0]; xr1v[p] = xp[1]; xr2v[p] = xp[2];
    const float* xq = x + (size_t)ce * 42 + mrc * 3;
    xc0v[p] = xq[0]; xc1v[p] = xq[1]; xc2v[p] = xq[2];
    bCv[p] = zero8; aRv[p] = zero8;
    if (quad < 2) {
      bCv[p] = *(const bf16x8*)&attrS[(size_t)ce * 256 + mr * 16 + quad * 8];
      aRv[p] = *(const bf16x8*)&attrS[(size_t)re * 256 + mr * 16 + quad * 8];
    }
  }
#pragma unroll
  for (int p = 0; p < 4; p++) {
    const int e = wave * 4 + p;
    if (quad == 0 && mr < 14) {
      s_xr[e][mr * 3 + 0] = xr0v[p];
      s_xr[e][mr * 3 + 1] = xr1v[p];
      s_xr[e][mr * 3 + 2] = xr2v[p];
    }
  }

  // ---- einsum chains: each wave owns 4 edges ----
#pragma unroll
  for (int p = 0; p < 4; p++) {
    const int e = wave * 4 + p;
    const float xr0 = xr0v[p], xr1 = xr1v[p], xr2 = xr2v[p];
    const float xc0 = xc0v[p], xc1 = xc1v[p], xc2 = xc2v[p];
    // Gram cross-term: G[row=j][col=i] = xc_j . xr_i  (K=3, operands in-regs)
    bf16x8 aX = zero8, bX = zero8;
    if (quad == 0) {
      aX[0] = f2bs(xc0); aX[1] = f2bs(xc1); aX[2] = f2bs(xc2);
      bX[0] = f2bs(xr0); bX[1] = f2bs(xr1); bX[2] = f2bs(xr2);
    }
    f32x4 G = __builtin_amdgcn_mfma_f32_16x16x32_bf16(aX, bX, zacc, 0, 0, 0);
    const float nr = xr0 * xr0 + xr1 * xr1 + xr2 * xr2;
    const float nc = xc0 * xc0 + xc1 * xc1 + xc2 * xc2;
    float dD[4];
#pragma unroll
    for (int r = 0; r < 4; r++) {
      float ncj = __shfl(nc, quad * 4 + r);
      dD[r] = sqrtf(fmaxf(ncj + nr - 2.f * G[r], 0.f));
    }
    // transpose dists (D-layout) -> A-frag aD[m=i][k=j]
    bf16x8 aD;
#pragma unroll
    for (int jj = 0; jj < 8; jj++) {
      const int qs = (quad * 2 + (jj >> 2)) & 3;
      float dv = __shfl(dD[jj & 3], (qs << 4) | mr);
      if (quad >= 2) dv = 0.f;
      aD[jj] = f2bs(dv);
    }
    f32x4 m1 = __builtin_amdgcn_mfma_f32_16x16x32_bf16(aD, bCv[p], zacc, 0, 0, 0);
    bf16x8 bM;
#pragma unroll
    for (int jj = 0; jj < 8; jj++) {
      const int qs = (quad * 2 + (jj >> 2)) & 3;
      float mv = __shfl(m1[jj & 3], (qs << 4) | mr);
      if (quad >= 2) mv = 0.f;
      bM[jj] = f2bs(mv);
    }
    f32x4 rd = __builtin_amdgcn_mfma_f32_16x16x32_bf16(aRv[p], bM, zacc, 0, 0, 0);
    float ss = rd[0] * rd[0] + rd[1] * rd[1] + rd[2] * rd[2] + rd[3] * rd[3];
    ss += __shfl_xor(ss, 32); ss += __shfl_xor(ss, 16); ss += __shfl_xor(ss, 8);
    ss += __shfl_xor(ss, 4);  ss += __shfl_xor(ss, 2);  ss += __shfl_xor(ss, 1);
    if (lane == 0) s_rn[e] = sqrtf(ss) + 1.0f;
#pragma unroll
    for (int r = 0; r < 4; r++) {
      const int aa = quad * 4 + r;
      sW[aa >> 1][e][((aa & 1) << 4) | mr] = __float2bfloat16(rd[r]);
    }
  }
  __syncthreads();

  // ---- rad GEMM: radf = (radial @ rad_w + rad_b)/rn -> sA[8..11] ----
  {
    f32x4 acc0 = zacc, acc1 = zacc;
#pragma unroll
    for (int kb = 0; kb < 8; kb++) {
      bf16x8 a = *(const bf16x8*)&sW[kb][mr][quad * 8];
      const __hip_bfloat16* wp = wz_rad + ((size_t)(kb * 128 + n0 + mr) * 32 + quad * 8);
      bf16x8 b0 = *(const bf16x8*)wp;
      bf16x8 b1 = *(const bf16x8*)(wp + 16 * 32);
      acc0 = __builtin_amdgcn_mfma_f32_16x16x32_bf16(a, b0, acc0, 0, 0, 0);
      acc1 = __builtin_amdgcn_mfma_f32_16x16x32_bf16(a, b1, acc1, 0, 0, 0);
    }
    float bias0 = rad_b[n0 + mr], bias1 = rad_b[n0 + 16 + mr];
#pragma unroll
    for (int r = 0; r < 4; r++) {
      int e = quad * 4 + r;
      float inv = 1.f / s_rn[e];
      sA[8 + wave][e][mr]      = __float2bfloat16((acc0[r] + bias0) * inv);
      sA[8 + wave][e][16 + mr] = __float2bfloat16((acc1[r] + bias1) * inv);
    }
  }
  __syncthreads();
  // ---- stage 1: ef1 = silu(A @ e_w1 + e_b1), K=384 -> sT (=sW[0..3]) ----
  {
    f32x4 acc0 = zacc, acc1 = zacc;
#pragma unroll
    for (int kb = 0; kb < 12; kb++) {
      bf16x8 a = *(const bf16x8*)&sA[kb][mr][quad * 8];
      const __hip_bfloat16* wp = wz_e1 + ((size_t)(kb * 128 + n0 + mr) * 32 + quad * 8);
      bf16x8 b0 = *(const bf16x8*)wp;
      bf16x8 b1 = *(const bf16x8*)(wp + 16 * 32);
      acc0 = __builtin_amdgcn_mfma_f32_16x16x32_bf16(a, b0, acc0, 0, 0, 0);
      acc1 = __builtin_amdgcn_mfma_f32_16x16x32_bf16(a, b1, acc1, 0, 0, 0);
    }
    float bias0 = e_b1[n0 + mr], bias1 = e_b1[n0 + 16 + mr];
#pragma unroll
    for (int r = 0; r < 4; r++) {
      int e = quad * 4 + r;
      sW[wave][e][mr]      = __float2bfloat16(siluf(acc0[r] + bias0));
      sW[wave][e][16 + mr] = __float2bfloat16(siluf(acc1[r] + bias1));
    }
  }
  __syncthreads();
  // ---- stage 2: ef2 = silu(ef1 @ e_w2 + e_b2) -> sU (=sW[4..7]); gate partials ----
  {
    f32x4 acc0 = zacc, acc1 = zacc;
#pragma unroll
    for (int kb = 0; kb < 4; kb++) {
      bf16x8 a = *(const bf16x8*)&sW[kb][mr][quad * 8];
      const __hip_bfloat16* wp = wz_e2 + ((size_t)(kb * 128 + n0 + mr) * 32 + quad * 8);
      bf16x8 b0 = *(const bf16x8*)wp;
      bf16x8 b1 = *(const bf16x8*)(wp + 16 * 32);
      acc0 = __builtin_amdgcn_mfma_f32_16x16x32_bf16(a, b0, acc0, 0, 0, 0);
      acc1 = __builtin_amdgcn_mfma_f32_16x16x32_bf16(a, b1, acc1, 0, 0, 0);
    }
    float bias0 = e_b2[n0 + mr], bias1 = e_b2[n0 + 16 + mr];
    float part[4];
#pragma unroll
    for (int r = 0; r < 4; r++) {
      int e = quad * 4 + r;
      float v0 = siluf(acc0[r] + bias0);
      float v1 = siluf(acc1[r] + bias1);
      sW[4 + wave][e][mr]      = __float2bfloat16(v0);
      sW[4 + wave][e][16 + mr] = __float2bfloat16(v1);
      part[r] = v0 * aw0 + v1 * aw1;
    }
    // in-quad reduce over mr (16 lanes)
#pragma unroll
    for (int msk = 1; msk < 16; msk <<= 1) {
#pragma unroll
      for (int r = 0; r < 4; r++) part[r] += __shfl_xor(part[r], msk);
    }
    if (mr == 0) {
#pragma unroll
      for (int r = 0; r < 4; r++) s_red4[wave * 16 + quad * 4 + r] = part[r];
    }
  }
  __syncthreads();
  // ---- attention gate: sum the 4 wave-partials ----
  if (t < TE) {
    float s = s_red4[t] + s_red4[16 + t] + s_red4[32 + t] + s_red4[48 + t];
    s_att[t] = sigmf(s + att_b0);
  }
  __syncthreads();
  // ---- stage 3: cmh = silu(att*(ef2 @ c_w1) + c_b1) -> sV (=sW[0..3]) ----
  {
    f32x4 acc0 = zacc, acc1 = zacc;
#pragma unroll
    for (int kb = 0; kb < 4; kb++) {
      bf16x8 a = *(const bf16x8*)&sW[4 + kb][mr][quad * 8];
      const __hip_bfloat16* wp = wz_c1 + ((size_t)(kb * 128 + n0 + mr) * 32 + quad * 8);
      bf16x8 b0 = *(const bf16x8*)wp;
      bf16x8 b1 = *(const bf16x8*)(wp + 16 * 32);
      acc0 = __builtin_amdgcn_mfma_f32_16x16x32_bf16(a, b0, acc0, 0, 0, 0);
      acc1 = __builtin_amdgcn_mfma_f32_16x16x32_bf16(a, b1, acc1, 0, 0, 0);
    }
    float bias0 = c_b1[n0 + mr], bias1 = c_b1[n0 + 16 + mr];
#pragma unroll
    for (int r = 0; r < 4; r++) {
      int e = quad * 4 + r;
      float av = s_att[e];
      sW[wave][e][mr]      = __float2bfloat16(siluf(av * acc0[r] + bias0));
      sW[wave][e][16 + mr] = __float2bfloat16(siluf(av * acc1[r] + bias1));
    }
  }
  __syncthreads();
  // ---- cm = cmh @ c_w2 + c_b2 via MFMA (wave 0 only) ----
  if (wave == 0) {
    f32x4 acc = zacc;
#pragma unroll
    for (int kb = 0; kb < 4; kb++) {
      bf16x8 a = *(const bf16x8*)&sW[kb][mr][quad * 8];
      bf16x8 b = *(const bf16x8*)(wz_c2 + ((size_t)(kb * 16 + mr) * 32 + quad * 8));
      acc = __builtin_amdgcn_mfma_f32_16x16x32_bf16(a, b, acc, 0, 0, 0);
    }
    if (mr < 14) {
      float bias = c_b2[mr];
#pragma unroll
      for (int r = 0; r < 4; r++) s_cm[(quad * 4 + r) * 14 + mr] = acc[r] + bias;
    }
  }
  __syncthreads();
  // ---- RollerPooling ----
  if (t < TE * 14) {
    int e = t / 14, c = t % 14;
    int wsz = 15 - s_cs[e];
    int hi = min(c + wsz, 14);
    float s = 0.f;
    for (int j = c; j < hi; j++) s += s_cm[e * 14 + j];
    s_pool[e * 14 + c] = s / (float)wsz;
  }
  __syncthreads();
  // ---- trans scatter (packed bf16 atomics) ----
  for (int i = t; i < TE * 21; i += 256) {
    int e = i / 21, pr = i % 21;
    if (e < ne) {
      int r0 = pr * 2, r1 = r0 + 1;
      float v0 = (s_xr[e][r0] - s_pc[e][r0 % 3]) * s_pool[e * 14 + r0 / 3];
      float v1 = (s_xr[e][r1] - s_pc[e][r1 % 3]) * s_pool[e * 14 + r1 / 3];
      unsafeAtomicAdd(&x_acc[(size_t)s_row[e] * 21 + pr], mk_bf162(v0, v1));
    }
  }
  // ---- agg scatter (gated ef2, packed bf16 atomics) ----
  for (int i = t; i < TE * 64; i += 256) {
    int e = i >> 6, o2 = i & 63;
    if (e < ne) {
      float av = s_att[e];
      const __hip_bfloat16* wp2 = &sW[4 + (o2 >> 4)][e][(o2 & 15) * 2];
      float v0 = __bfloat162float(wp2[0]) * av;
      float v1 = __bfloat162float(wp2[1]) * av;
      unsafeAtomicAdd(&agg[(size_t)s_col[e] * 64 + o2], mk_bf162(v0, v1));
    }
  }
}

// ---- node MLP (MFMA) + residual + in-wave LayerNorm + fused x_new ----
__global__ __launch_bounds__(256) void k_node(
    const float* __restrict__ h, const __hip_bfloat162* __restrict__ agg,
    const unsigned* __restrict__ cnt_col,
    const __hip_bfloat16* __restrict__ wz_n1, const float* __restrict__ n_b1,
    const __hip_bfloat16* __restrict__ wz_n2, const float* __restrict__ n_b2,
    const float* __restrict__ ln_g, const float* __restrict__ ln_b,
    const float* __restrict__ x, const __hip_bfloat162* __restrict__ x_acc,
    const unsigned* __restrict__ cnt_row,
    float* __restrict__ out_h, float* __restrict__ out_x, int Nn) {
  __shared__ __hip_bfloat16 sA[8][16][PAD];
  __shared__ __hip_bfloat16 sT[4][16][PAD];
  __shared__ float s_h[TN][128];
  __shared__ float s_o[TN][132];
  const int t = threadIdx.x;
  const int nb0 = blockIdx.x * TN;
  const int nn = min(TN, Nn - nb0);

  // fused x_new
  for (int i = t; i < TN * 21; i += 256) {
    int n = i / 21, pr = i % 21;
    if (n < nn) {
      int gn = nb0 + n;
      unsigned c = cnt_row[gn];
      float inv = 1.f / (float)(c > 0 ? c : 1);
      float2 xa = __bfloat1622float2(x_acc[(size_t)gn * 21 + pr]);
      size_t gi = (size_t)gn * 42 + pr * 2;
      out_x[gi]     = x[gi] + xa.x * inv;
      out_x[gi + 1] = x[gi + 1] + xa.y * inv;
    }
  }

  for (int i = t; i < TN * 64; i += 256) {
    int m = i >> 6, kp = (i & 63) << 1;
    int kb = kp >> 5, kk = kp & 31;
    int gn = nb0 + min(m, nn - 1);
    const float2 hv = *(const float2*)&h[(size_t)gn * 128 + kp];
    sA[kb][m][kk]     = __float2bfloat16(hv.x);
    sA[kb][m][kk + 1] = __float2bfloat16(hv.y);
    s_h[m][kp]     = hv.x;
    s_h[m][kp + 1] = hv.y;
    unsigned c = cnt_col[gn];
    float inv = 1.f / (float)(c > 0 ? c : 1);
    float2 gv = __bfloat1622float2(agg[(size_t)gn * 64 + (kp >> 1)]);
    sA[4 + kb][m][kk]     = __float2bfloat16(gv.x * inv);
    sA[4 + kb][m][kk + 1] = __float2bfloat16(gv.y * inv);
  }
  __syncthreads();
  const int lane = t & 63, wave = t >> 6, quad = lane >> 4, mr = lane & 15;
  const int n0 = wave * 32;
  f32x4 zacc = {0.f, 0.f, 0.f, 0.f};
  {
    f32x4 acc0 = zacc, acc1 = zacc;
#pragma unroll
    for (int kb = 0; kb < 8; kb++) {
      bf16x8 a = *(const bf16x8*)&sA[kb][mr][quad * 8];
      const __hip_bfloat16* wp = wz_n1 + ((size_t)(kb * 128 + n0 + mr) * 32 + quad * 8);
      bf16x8 b0 = *(const bf16x8*)wp;
      bf16x8 b1 = *(const bf16x8*)(wp + 16 * 32);
      acc0 = __builtin_amdgcn_mfma_f32_16x16x32_bf16(a, b0, acc0, 0, 0, 0);
      acc1 = __builtin_amdgcn_mfma_f32_16x16x32_bf16(a, b1, acc1, 0, 0, 0);
    }
    float bias0 = n_b1[n0 + mr], bias1 = n_b1[n0 + 16 + mr];
#pragma unroll
    for (int r = 0; r < 4; r++) {
      int m = quad * 4 + r;
      sT[wave][m][mr]      = __float2bfloat16(siluf(acc0[r] + bias0));
      sT[wave][m][16 + mr] = __float2bfloat16(siluf(acc1[r] + bias1));
    }
  }
  __syncthreads();
  {
    f32x4 acc0 = zacc, acc1 = zacc;
#pragma unroll
    for (int kb = 0; kb < 4; kb++) {
      bf16x8 a = *(const bf16x8*)&sT[kb][mr][quad * 8];
      const __hip_bfloat16* wp = wz_n2 + ((size_t)(kb * 128 + n0 + mr) * 32 + quad * 8);
      bf16x8 b0 = *(const bf16x8*)wp;
      bf16x8 b1 = *(const bf16x8*)(wp + 16 * 32);
      acc0 = __builtin_amdgcn_mfma_f32_16x16x32_bf16(a, b0, acc0, 0, 0, 0);
      acc1 = __builtin_amdgcn_mfma_f32_16x16x32_bf16(a, b1, acc1, 0, 0, 0);
    }
    float bias0 = n_b2[n0 + mr], bias1 = n_b2[n0 + 16 + mr];
#pragma unroll
    for (int r = 0; r < 4; r++) {
      int m = quad * 4 + r;
      s_o[m][n0 + mr]      = s_h[m][n0 + mr] + acc0[r] + bias0;
      s_o[m][n0 + 16 + mr] = s_h[m][n0 + 16 + mr] + acc1[r] + bias1;
    }
  }
  __syncthreads();
  // ---- in-wave LayerNorm: node n's 16 threads are contiguous lanes ----
  {
    int n = t >> 4, p = t & 15;
    float v[8];
    float s = 0.f;
#pragma unroll
    for (int j = 0; j < 8; j++) {
      v[j] = s_o[n][p * 8 + j];
      s += v[j];
    }
    s += __shfl_xor(s, 1); s += __shfl_xor(s, 2);
    s += __shfl_xor(s, 4); s += __shfl_xor(s, 8);
    float mu = s * (1.f / 128.f);
    float var = 0.f;
#pragma unroll
    for (int j = 0; j < 8; j++) {
      float d = v[j] - mu;
      var += d * d;
    }
    var += __shfl_xor(var, 1); var += __shfl_xor(var, 2);
    var += __shfl_xor(var, 4); var += __shfl_xor(var, 8);
    float rs = rsqrtf(var * (1.f / 128.f) + 1e-5f);
    if (n < nn) {
      size_t base = (size_t)(nb0 + n) * 128 + p * 8;
#pragma unroll
      for (int j = 0; j < 8; j++)
        out_h[base + j] = (v[j] - mu) * rs * ln_g[p * 8 + j] + ln_b[p * 8 + j];
    }
  }
}

extern "C" void kernel_launch(void* const* d_in, const int* in_sizes, int n_in,
                              void* d_out, int out_size, void* d_ws, size_t ws_size,
                              hipStream_t stream) {
  const float* h     = (const float*)d_in[0];
  const float* x     = (const float*)d_in[1];
  const float* attr  = (const float*)d_in[2];
  const float* cw    = (const float*)d_in[3];
  const int*   row   = (const int*)d_in[4];
  const int*   col   = (const int*)d_in[5];
  const float* rad_w = (const float*)d_in[6];
  const float* rad_b = (const float*)d_in[7];
  const float* e_w1  = (const float*)d_in[8];
  const float* e_b1  = (const float*)d_in[9];
  const float* e_w2  = (const float*)d_in[10];
  const float* e_b2  = (const float*)d_in[11];
  const float* att_w = (const float*)d_in[12];
  const float* att_b = (const float*)d_in[13];
  const float* c_w1  = (const float*)d_in[14];
  const float* c_b1  = (const float*)d_in[15];
  const float* c_w2  = (const float*)d_in[16];
  const float* c_b2  = (const float*)d_in[17];
  const float* n_w1  = (const float*)d_in[18];
  const float* n_b1  = (const float*)d_in[19];
  const float* n_w2  = (const float*)d_in[20];
  const float* n_b2  = (const float*)d_in[21];
  const float* ln_g  = (const float*)d_in[22];
  const float* ln_b  = (const float*)d_in[23];

  const int N = in_sizes[0] / 128;
  const int E = in_sizes[4];

  char* ws = (char*)d_ws;
  size_t off = 0;
  auto alloc = [&](size_t bytes) {
    size_t o = off;
    off += (bytes + 255) & ~(size_t)255;
    return o;
  };
  size_t off_wzr  = alloc(32768 * sizeof(__hip_bfloat16));
  size_t off_wz1  = alloc(49152 * sizeof(__hip_bfloat16));
  size_t off_wz2  = alloc(16384 * sizeof(__hip_bfloat16));
  size_t off_wzc  = alloc(16384 * sizeof(__hip_bfloat16));
  size_t off_wzn1 = alloc(32768 * sizeof(__hip_bfloat16));
  size_t off_wzn2 = alloc(16384 * sizeof(__hip_bfloat16));
  size_t off_wzc2 = alloc(2048 * sizeof(__hip_bfloat16));
  size_t off_atS  = alloc((size_t)N * 256 * sizeof(__hip_bfloat16));
  size_t off_hb   = alloc((size_t)N * 128 * sizeof(__hip_bfloat16));
  size_t off_px   = alloc((size_t)N * 3 * sizeof(float));
  size_t off_cs   = alloc((size_t)N * sizeof(int));
  size_t off_cntr = alloc((size_t)N * sizeof(unsigned));
  size_t off_cntc = alloc((size_t)N * sizeof(unsigned));
  size_t off_xacc = alloc((size_t)N * 21 * sizeof(__hip_bfloat162));
  size_t off_agg  = alloc((size_t)N * 64 * sizeof(__hip_bfloat162));

  __hip_bfloat16* wz_rad = (__hip_bfloat16*)(ws + off_wzr);
  __hip_bfloat16* wz_e1  = (__hip_bfloat16*)(ws + off_wz1);
  __hip_bfloat16* wz_e2  = (__hip_bfloat16*)(ws + off_wz2);
  __hip_bfloat16* wz_c1  = (__hip_bfloat16*)(ws + off_wzc);
  __hip_bfloat16* wz_n1  = (__hip_bfloat16*)(ws + off_wzn1);
  __hip_bfloat16* wz_n2  = (__hip_bfloat16*)(ws + off_wzn2);
  __hip_bfloat16* wz_c2  = (__hip_bfloat16*)(ws + off_wzc2);
  __hip_bfloat16* attrS  = (__hip_bfloat16*)(ws + off_atS);
  __hip_bfloat16* hb     = (__hip_bfloat16*)(ws + off_hb);
  float* pooled_x   = (float*)(ws + off_px);
  int* chsum        = (int*)(ws + off_cs);
  unsigned* cnt_row = (unsigned*)(ws + off_cntr);
  unsigned* cnt_col = (unsigned*)(ws + off_cntc);
  __hip_bfloat162* x_acc = (__hip_bfloat162*)(ws + off_xacc);
  __hip_bfloat162* agg   = (__hip_bfloat162*)(ws + off_agg);

  (void)hipMemsetAsync(ws + off_cntr, 0, off - off_cntr, stream);

  const int pack_items = 165888 + N * 256 + N * 128 + N;
  k_pack<<<dim3((pack_items + 255) / 256), dim3(256), 0, stream>>>(
      h, x, attr, cw, rad_w, e_w1, e_w2, c_w1, n_w1, n_w2, c_w2,
      wz_rad, wz_e1, wz_e2, wz_c1, wz_n1, wz_n2, wz_c2,
      attrS, hb, pooled_x, chsum, N);
  k_edge<<<dim3((E + TE - 1) / TE), dim3(256), 0, stream>>>(
      hb, x, attrS, row, col, pooled_x, chsum,
      wz_rad, rad_b, wz_e1, e_b1, wz_e2, e_b2, att_w, att_b,
      wz_c1, c_b1, wz_c2, c_b2, cnt_row, cnt_col, x_acc, agg, E);
  k_node<<<dim3((N + TN - 1) / TN), dim3(256), 0, stream>>>(
      h, agg, cnt_col, wz_n1, n_b1, wz_n2, n_b2, ln_g, ln_b,
      x, x_acc, cnt_row, (float*)d_out, (float*)d_out + (size_t)N * 128, N);
}